// Round 2
// baseline (2837.984 us; speedup 1.0000x reference)
//
#include <hip/hip_runtime.h>
#include <math.h>

#define NAUTH 100000
#define NPAP  200000
#define DIM   128
#define ELIKE 600000
#define ECO   600000
#define BATCH 16384
#define EPSW  1e-8f

static_assert(ELIKE == ECO, "degree kernel assumes equal edge counts");

// ---------------------------------------------------------------------------
// Degree histogram: da = out-deg(like_src), dp = out-deg(like_dst),
// dcs/dcd = degrees of co_src/co_dst. Plain f32 atomics; avg degree ~6 so
// contention is negligible.
// ---------------------------------------------------------------------------
__global__ __launch_bounds__(256) void degree_kernel(
    const int* __restrict__ like_src, const int* __restrict__ like_dst,
    const int* __restrict__ co_src,   const int* __restrict__ co_dst,
    float* __restrict__ da, float* __restrict__ dp,
    float* __restrict__ dcs, float* __restrict__ dcd)
{
    int stride = gridDim.x * blockDim.x;
    for (int i = blockIdx.x * blockDim.x + threadIdx.x; i < ELIKE; i += stride) {
        atomicAdd(&da[like_src[i]],  1.0f);
        atomicAdd(&dp[like_dst[i]],  1.0f);
        atomicAdd(&dcs[co_src[i]],   1.0f);
        atomicAdd(&dcd[co_dst[i]],   1.0f);
    }
}

// ---------------------------------------------------------------------------
// Per-edge symmetric-norm coefficients (reused across passes/layers).
// 1/sqrtf matches lax.rsqrt within f32 tolerance.
// ---------------------------------------------------------------------------
__global__ __launch_bounds__(256) void coef_kernel(
    const int* __restrict__ like_src, const int* __restrict__ like_dst,
    const int* __restrict__ co_src,   const int* __restrict__ co_dst,
    const float* __restrict__ da,  const float* __restrict__ dp,
    const float* __restrict__ dcs, const float* __restrict__ dcd,
    float* __restrict__ like_coef, float* __restrict__ co_coef)
{
    int stride = gridDim.x * blockDim.x;
    for (int i = blockIdx.x * blockDim.x + threadIdx.x; i < ELIKE; i += stride) {
        int ls = like_src[i], ld = like_dst[i];
        int cs = co_src[i],   cd = co_dst[i];
        like_coef[i] = 1.0f / sqrtf(fmaxf(da[ls] * dp[ld], 1.0f));
        co_coef[i]   = 1.0f / sqrtf(fmaxf(dcs[cs] * dcd[cd], 1.0f));
    }
}

// ---------------------------------------------------------------------------
// out[i,:] = scale * (1 - deg[i]/(deg[i]+eps)) * emb[i,:]   (float4 per thread)
// Used for wr_a1/wr_p1 init (scale=1) and a2buf init from wr_a1 (scale=0.5).
// Writing the full buffer also clears the 0xAA ws poison ahead of the atomic
// scatters, so no extra memset is needed for these buffers.
// ---------------------------------------------------------------------------
__global__ __launch_bounds__(256) void node_scale_kernel(
    const float* __restrict__ emb, const float* __restrict__ deg,
    float* __restrict__ out, float scale, int n_nodes)
{
    int stride = gridDim.x * blockDim.x;
    int total  = n_nodes * (DIM / 4);
    for (int i = blockIdx.x * blockDim.x + threadIdx.x; i < total; i += stride) {
        int   node = i >> 5;                  // i / (DIM/4)
        float d    = deg[node];
        float sw   = (1.0f - d / (d + EPSW)) * scale;
        float4 v   = ((const float4*)emb)[i];
        float4 o;
        o.x = v.x * sw; o.y = v.y * sw; o.z = v.z * sw; o.w = v.w * sw;
        ((float4*)out)[i] = o;
    }
}

// ---------------------------------------------------------------------------
// Generic edge scatter: out[sidx[e],:] += scale*coef[e] * src[gidx[e],:].
// One wave (64 lanes x float2) per 512B row: gather and atomic scatter are
// both coalesced contiguous 512B bursts. Per-edge scalars are loaded by lane 0
// and broadcast via shfl (saves 3x63 redundant L1 loads per edge).
// ---------------------------------------------------------------------------
__global__ __launch_bounds__(256) void scatter_kernel(
    const float* __restrict__ src_emb, float* __restrict__ out,
    const int* __restrict__ gidx, const int* __restrict__ sidx,
    const float* __restrict__ coef, float scale, int nE)
{
    int lane  = threadIdx.x & 63;
    int wpb   = blockDim.x >> 6;
    int wave0 = blockIdx.x * wpb + (threadIdx.x >> 6);
    int wstr  = gridDim.x * wpb;
    for (int e = wave0; e < nE; e += wstr) {
        int g = 0, s = 0;
        float c = 0.0f;
        if (lane == 0) {            // one load, wave-broadcast
            g = gidx[e];
            s = sidx[e];
            c = coef[e] * scale;
        }
        g = __shfl(g, 0);
        s = __shfl(s, 0);
        c = __shfl(c, 0);
        float2 v = ((const float2*)(src_emb + (size_t)g * DIM))[lane];
        float* d = out + (size_t)s * DIM + lane * 2;
        atomicAdd(d,     v.x * c);
        atomicAdd(d + 1, v.y * c);
    }
}

// ---------------------------------------------------------------------------
// Final: gather final_author = emb + 0.5*co_a1 + 0.5*wr_a1 + a2buf at the B
// query rows only (full final_author is never materialized), dot with paper
// row, sigmoid. One wave per batch element.
// ---------------------------------------------------------------------------
__global__ __launch_bounds__(256) void final_kernel(
    const float* __restrict__ author_emb, const float* __restrict__ paper_emb,
    const int* __restrict__ authors, const int* __restrict__ papers,
    const float* __restrict__ co_a1, const float* __restrict__ wr_a1,
    const float* __restrict__ a2buf,
    float* __restrict__ out_pred, float* __restrict__ out_a, float* __restrict__ out_p)
{
    int lane  = threadIdx.x & 63;
    int wpb   = blockDim.x >> 6;
    int wave0 = blockIdx.x * wpb + (threadIdx.x >> 6);
    int wstr  = gridDim.x * wpb;
    for (int b = wave0; b < BATCH; b += wstr) {
        int a = authors[b];
        int p = papers[b];
        size_t arow = (size_t)a * DIM;
        size_t prow = (size_t)p * DIM;
        float2 e  = ((const float2*)(author_emb + arow))[lane];
        float2 c1 = ((const float2*)(co_a1 + arow))[lane];
        float2 w1 = ((const float2*)(wr_a1 + arow))[lane];
        float2 a2 = ((const float2*)(a2buf + arow))[lane];
        float fx = e.x + 0.5f * c1.x + 0.5f * w1.x + a2.x;
        float fy = e.y + 0.5f * c1.y + 0.5f * w1.y + a2.y;
        float2 pp = ((const float2*)(paper_emb + prow))[lane];
        ((float2*)(out_a + (size_t)b * DIM))[lane] = make_float2(fx, fy);
        ((float2*)(out_p + (size_t)b * DIM))[lane] = pp;
        float dot = fx * pp.x + fy * pp.y;
        #pragma unroll
        for (int off = 32; off; off >>= 1) dot += __shfl_xor(dot, off);
        if (lane == 0) out_pred[b] = 1.0f / (1.0f + expf(-dot));
    }
}

extern "C" void kernel_launch(void* const* d_in, const int* in_sizes, int n_in,
                              void* d_out, int out_size, void* d_ws, size_t ws_size,
                              hipStream_t stream) {
    const float* author_emb = (const float*)d_in[0];
    const float* paper_emb  = (const float*)d_in[1];
    const int*   authors    = (const int*)d_in[2];
    const int*   papers     = (const int*)d_in[3];
    const int*   like_src   = (const int*)d_in[4];
    const int*   like_dst   = (const int*)d_in[5];
    const int*   co_src     = (const int*)d_in[6];
    const int*   co_dst     = (const int*)d_in[7];

    // ---- workspace carve-up (256B aligned) ----
    size_t off = 0;
    auto alloc = [&](size_t bytes) -> float* {
        float* p = (float*)((char*)d_ws + off);
        off += (bytes + 255) & ~(size_t)255;
        return p;
    };
    float* da        = alloc((size_t)NAUTH * 4);
    float* dp        = alloc((size_t)NPAP  * 4);
    float* dcs       = alloc((size_t)NAUTH * 4);
    float* dcd       = alloc((size_t)NAUTH * 4);
    size_t deg_bytes = off;                       // contiguous degree region
    float* like_coef = alloc((size_t)ELIKE * 4);
    float* co_coef   = alloc((size_t)ECO   * 4);
    float* co_a1     = alloc((size_t)NAUTH * DIM * 4);
    float* wr_a1     = alloc((size_t)NAUTH * DIM * 4);
    float* wr_p1     = alloc((size_t)NPAP  * DIM * 4);
    float* a2buf     = alloc((size_t)NAUTH * DIM * 4);

    float* out_pred = (float*)d_out;              // [B]
    float* out_a    = out_pred + BATCH;           // [B,D]
    float* out_p    = out_a + (size_t)BATCH * DIM;// [B,D]

    // ---- zero what the atomics accumulate into ----
    hipMemsetAsync(d_ws, 0, deg_bytes, stream);                    // degrees
    hipMemsetAsync(co_a1, 0, (size_t)NAUTH * DIM * 4, stream);     // co_conv L1 acc

    // ---- degrees + coefs ----
    degree_kernel<<<2344, 256, 0, stream>>>(like_src, like_dst, co_src, co_dst,
                                            da, dp, dcs, dcd);
    coef_kernel<<<2344, 256, 0, stream>>>(like_src, like_dst, co_src, co_dst,
                                          da, dp, dcs, dcd, like_coef, co_coef);

    // ---- layer 1 ----
    // wr_a1 = u_sw * author_emb ; wr_p1 = i_sw * paper_emb
    node_scale_kernel<<<4096, 256, 0, stream>>>(author_emb, da, wr_a1, 1.0f, NAUTH);
    node_scale_kernel<<<4096, 256, 0, stream>>>(paper_emb,  dp, wr_p1, 1.0f, NPAP);
    // co_a1 += co_coef * author_emb[co_src]  -> co_dst
    scatter_kernel<<<8192, 256, 0, stream>>>(author_emb, co_a1, co_src, co_dst,
                                             co_coef, 1.0f, ECO);
    // wr_a1 += like_coef * paper_emb[like_dst] -> like_src
    scatter_kernel<<<8192, 256, 0, stream>>>(paper_emb, wr_a1, like_dst, like_src,
                                             like_coef, 1.0f, ELIKE);
    // wr_p1 += like_coef * author_emb[like_src] -> like_dst
    scatter_kernel<<<8192, 256, 0, stream>>>(author_emb, wr_p1, like_src, like_dst,
                                             like_coef, 1.0f, ELIKE);

    // ---- layer 2 (a2buf accumulates 0.5*co_a2 + 0.5*wr_a2; _wr_p2 is dead) ----
    // a2buf = 0.5 * u_sw * wr_a1
    node_scale_kernel<<<4096, 256, 0, stream>>>(wr_a1, da, a2buf, 0.5f, NAUTH);
    // a2buf += 0.5 * co_coef * co_a1[co_src] -> co_dst
    scatter_kernel<<<8192, 256, 0, stream>>>(co_a1, a2buf, co_src, co_dst,
                                             co_coef, 0.5f, ECO);
    // a2buf += 0.5 * like_coef * wr_p1[like_dst] -> like_src
    scatter_kernel<<<8192, 256, 0, stream>>>(wr_p1, a2buf, like_dst, like_src,
                                             like_coef, 0.5f, ELIKE);

    // ---- scoring ----
    final_kernel<<<4096, 256, 0, stream>>>(author_emb, paper_emb, authors, papers,
                                           co_a1, wr_a1, a2buf,
                                           out_pred, out_a, out_p);
}

// Round 9
// 825.025 us; speedup vs baseline: 3.4399x; 3.4399x over previous
//
#include <hip/hip_runtime.h>
#include <math.h>

#define NAUTH 100000
#define NPAP  200000
#define DIM   128
#define ELIKE 600000
#define ECO   600000
#define BATCH 16384
#define EPSW  1e-8f

static_assert(ELIKE == ECO, "degree kernel assumes equal edge counts");

// ===========================================================================
// Stage 1: integer degree histograms.
// ===========================================================================
__global__ __launch_bounds__(256) void degree_kernel(
    const int* __restrict__ like_src, const int* __restrict__ like_dst,
    const int* __restrict__ co_src,   const int* __restrict__ co_dst,
    int* __restrict__ deg_ls, int* __restrict__ deg_ld,
    int* __restrict__ deg_cs, int* __restrict__ deg_cd)
{
    int stride = gridDim.x * blockDim.x;
    for (int i = blockIdx.x * blockDim.x + threadIdx.x; i < ELIKE; i += stride) {
        atomicAdd(&deg_ls[like_src[i]], 1);
        atomicAdd(&deg_ld[like_dst[i]], 1);
        atomicAdd(&deg_cs[co_src[i]],   1);
        atomicAdd(&deg_cd[co_dst[i]],   1);
    }
}

// ===========================================================================
// Stage 2: 3-stage exclusive scan of a degree array -> segment cursors.
// ===========================================================================
#define SCAN_CHUNK 1024

__global__ __launch_bounds__(256) void scan_block_sums(
    const int* __restrict__ deg, int* __restrict__ bsum, int n)
{
    __shared__ int sd[256];
    int t = threadIdx.x;
    int base = blockIdx.x * SCAN_CHUNK + t * 4;
    int s = 0;
    #pragma unroll
    for (int j = 0; j < 4; ++j) { int idx = base + j; if (idx < n) s += deg[idx]; }
    sd[t] = s; __syncthreads();
    for (int o = 128; o > 0; o >>= 1) { if (t < o) sd[t] += sd[t + o]; __syncthreads(); }
    if (t == 0) bsum[blockIdx.x] = sd[0];
}

__global__ void scan_serial(int* __restrict__ bsum, int nb)
{
    if (threadIdx.x == 0 && blockIdx.x == 0) {
        int run = 0;
        for (int i = 0; i < nb; ++i) { int v = bsum[i]; bsum[i] = run; run += v; }
    }
}

__global__ __launch_bounds__(256) void scan_write_cur(
    const int* __restrict__ deg, const int* __restrict__ bsum,
    int* __restrict__ cur, int n)
{
    __shared__ int sd[256];
    int t = threadIdx.x;
    int base = blockIdx.x * SCAN_CHUNK + t * 4;
    int d[4]; int s = 0;
    #pragma unroll
    for (int j = 0; j < 4; ++j) {
        int idx = base + j;
        d[j] = (idx < n) ? deg[idx] : 0;
        s += d[j];
    }
    sd[t] = s; __syncthreads();
    for (int o = 1; o < 256; o <<= 1) {
        int v = (t >= o) ? sd[t - o] : 0;
        __syncthreads();
        sd[t] += v;
        __syncthreads();
    }
    int excl = sd[t] - s + bsum[blockIdx.x];
    #pragma unroll
    for (int j = 0; j < 4; ++j) {
        int idx = base + j;
        if (idx < n) { cur[idx] = excl; excl += d[j]; }
    }
}

// ===========================================================================
// Stage 3: counting-sort placement with inline coef computation.
// After this kernel, cur[n] == segment_end(n); start = cur[n] - deg[n].
// ===========================================================================
__global__ __launch_bounds__(256) void placement_kernel(
    const int* __restrict__ like_src, const int* __restrict__ like_dst,
    const int* __restrict__ co_src,   const int* __restrict__ co_dst,
    const int* __restrict__ deg_ls, const int* __restrict__ deg_ld,
    const int* __restrict__ deg_cs, const int* __restrict__ deg_cd,
    int* __restrict__ cur_ls, int* __restrict__ cur_ld, int* __restrict__ cur_cd,
    int2* __restrict__ pairs_ls, int2* __restrict__ pairs_ld,
    int2* __restrict__ pairs_cd)
{
    int stride = gridDim.x * blockDim.x;
    for (int i = blockIdx.x * blockDim.x + threadIdx.x; i < ELIKE; i += stride) {
        int ls = like_src[i], ld = like_dst[i];
        float lc = 1.0f / sqrtf(fmaxf((float)deg_ls[ls] * (float)deg_ld[ld], 1.0f));
        int lcb = __float_as_int(lc);
        int s1 = atomicAdd(&cur_ls[ls], 1);
        pairs_ls[s1] = make_int2(ld, lcb);          // by like_src, gather paper
        int s2 = atomicAdd(&cur_ld[ld], 1);
        pairs_ld[s2] = make_int2(ls, lcb);          // by like_dst, gather author

        int cs = co_src[i], cd = co_dst[i];
        float cc = 1.0f / sqrtf(fmaxf((float)deg_cs[cs] * (float)deg_cd[cd], 1.0f));
        int s3 = atomicAdd(&cur_cd[cd], 1);
        pairs_cd[s3] = make_int2(cs, __float_as_int(cc)); // by co_dst, gather author
    }
}

// ===========================================================================
// Segmented gather: acc += sum over segment of coef * src[gidx, :]
// One wave (64 lanes x float2 = 512B row); pairs broadcast via shfl.
// ===========================================================================
__device__ __forceinline__ void seg_acc(
    const int2* __restrict__ pairs, int start, int end, int lane,
    const float* __restrict__ src, float2& acc)
{
    for (int base = start; base < end; base += 64) {
        int m = end - base; if (m > 64) m = 64;
        int2 pr = make_int2(0, 0);
        if (lane < m) pr = pairs[base + lane];
        for (int k = 0; k < m; ++k) {
            int   g = __shfl(pr.x, k);
            float c = __int_as_float(__shfl(pr.y, k));
            float2 v = ((const float2*)(src + (size_t)g * DIM))[lane];
            acc.x += v.x * c;
            acc.y += v.y * c;
        }
    }
}

// Layer-1 author pass (fused): co_a1[n] = sum(co);  wr_a1[n] = u_sw*emb + sum(like)
__global__ __launch_bounds__(256) void l1_author_kernel(
    const float* __restrict__ author_emb, const float* __restrict__ paper_emb,
    const int* __restrict__ cur_cd, const int* __restrict__ deg_cd,
    const int2* __restrict__ pairs_cd,
    const int* __restrict__ cur_ls, const int* __restrict__ deg_ls,
    const int2* __restrict__ pairs_ls,
    float* __restrict__ co_a1, float* __restrict__ wr_a1)
{
    int lane = threadIdx.x & 63;
    int n = blockIdx.x * (blockDim.x >> 6) + (threadIdx.x >> 6);
    if (n >= NAUTH) return;

    float2 accc = make_float2(0.f, 0.f);
    float2 accw = make_float2(0.f, 0.f);
    int ec = cur_cd[n], dc = deg_cd[n];
    seg_acc(pairs_cd, ec - dc, ec, lane, author_emb, accc);
    int el = cur_ls[n], dl = deg_ls[n];
    seg_acc(pairs_ls, el - dl, el, lane, paper_emb, accw);

    float d  = (float)dl;
    float sw = 1.0f - d / (d + EPSW);
    float2 base = ((const float2*)(author_emb + (size_t)n * DIM))[lane];
    float2 wr;
    wr.x = sw * base.x + accw.x;
    wr.y = sw * base.y + accw.y;
    ((float2*)(co_a1 + (size_t)n * DIM))[lane] = accc;
    ((float2*)(wr_a1 + (size_t)n * DIM))[lane] = wr;
}

// Layer-1 paper pass: wr_p1[n] = i_sw*emb + sum(like by dst)
__global__ __launch_bounds__(256) void l1_paper_kernel(
    const float* __restrict__ author_emb, const float* __restrict__ paper_emb,
    const int* __restrict__ cur_ld, const int* __restrict__ deg_ld,
    const int2* __restrict__ pairs_ld,
    float* __restrict__ wr_p1)
{
    int lane = threadIdx.x & 63;
    int n = blockIdx.x * (blockDim.x >> 6) + (threadIdx.x >> 6);
    if (n >= NPAP) return;

    float2 acc = make_float2(0.f, 0.f);
    int e = cur_ld[n], dg = deg_ld[n];
    seg_acc(pairs_ld, e - dg, e, lane, author_emb, acc);

    float d  = (float)dg;
    float sw = 1.0f - d / (d + EPSW);
    float2 base = ((const float2*)(paper_emb + (size_t)n * DIM))[lane];
    acc.x += sw * base.x;
    acc.y += sw * base.y;
    ((float2*)(wr_p1 + (size_t)n * DIM))[lane] = acc;
}

// Layer-2 author pass (fused, *0.5 folded):
//   a2buf[n] = 0.5*( u_sw*wr_a1[n] + sum(co: co_a1) + sum(like: wr_p1) )
__global__ __launch_bounds__(256) void l2_author_kernel(
    const float* __restrict__ co_a1, const float* __restrict__ wr_a1,
    const float* __restrict__ wr_p1,
    const int* __restrict__ cur_cd, const int* __restrict__ deg_cd,
    const int2* __restrict__ pairs_cd,
    const int* __restrict__ cur_ls, const int* __restrict__ deg_ls,
    const int2* __restrict__ pairs_ls,
    float* __restrict__ a2buf)
{
    int lane = threadIdx.x & 63;
    int n = blockIdx.x * (blockDim.x >> 6) + (threadIdx.x >> 6);
    if (n >= NAUTH) return;

    float2 acc = make_float2(0.f, 0.f);
    int ec = cur_cd[n], dc = deg_cd[n];
    seg_acc(pairs_cd, ec - dc, ec, lane, co_a1, acc);
    int el = cur_ls[n], dl = deg_ls[n];
    seg_acc(pairs_ls, el - dl, el, lane, wr_p1, acc);

    float d  = (float)dl;
    float sw = 1.0f - d / (d + EPSW);
    float2 base = ((const float2*)(wr_a1 + (size_t)n * DIM))[lane];
    acc.x = 0.5f * (acc.x + sw * base.x);
    acc.y = 0.5f * (acc.y + sw * base.y);
    ((float2*)(a2buf + (size_t)n * DIM))[lane] = acc;
}

// ===========================================================================
// Final scoring: one wave per batch element; full final_author never built.
// ===========================================================================
__global__ __launch_bounds__(256) void final_kernel(
    const float* __restrict__ author_emb, const float* __restrict__ paper_emb,
    const int* __restrict__ authors, const int* __restrict__ papers,
    const float* __restrict__ co_a1, const float* __restrict__ wr_a1,
    const float* __restrict__ a2buf,
    float* __restrict__ out_pred, float* __restrict__ out_a, float* __restrict__ out_p)
{
    int lane  = threadIdx.x & 63;
    int wpb   = blockDim.x >> 6;
    int wave0 = blockIdx.x * wpb + (threadIdx.x >> 6);
    int wstr  = gridDim.x * wpb;
    for (int b = wave0; b < BATCH; b += wstr) {
        int a = authors[b];
        int p = papers[b];
        size_t arow = (size_t)a * DIM;
        size_t prow = (size_t)p * DIM;
        float2 e  = ((const float2*)(author_emb + arow))[lane];
        float2 c1 = ((const float2*)(co_a1 + arow))[lane];
        float2 w1 = ((const float2*)(wr_a1 + arow))[lane];
        float2 a2 = ((const float2*)(a2buf + arow))[lane];
        float fx = e.x + 0.5f * c1.x + 0.5f * w1.x + a2.x;
        float fy = e.y + 0.5f * c1.y + 0.5f * w1.y + a2.y;
        float2 pp = ((const float2*)(paper_emb + prow))[lane];
        ((float2*)(out_a + (size_t)b * DIM))[lane] = make_float2(fx, fy);
        ((float2*)(out_p + (size_t)b * DIM))[lane] = pp;
        float dot = fx * pp.x + fy * pp.y;
        #pragma unroll
        for (int off = 32; off; off >>= 1) dot += __shfl_xor(dot, off);
        if (lane == 0) out_pred[b] = 1.0f / (1.0f + expf(-dot));
    }
}

extern "C" void kernel_launch(void* const* d_in, const int* in_sizes, int n_in,
                              void* d_out, int out_size, void* d_ws, size_t ws_size,
                              hipStream_t stream) {
    const float* author_emb = (const float*)d_in[0];
    const float* paper_emb  = (const float*)d_in[1];
    const int*   authors    = (const int*)d_in[2];
    const int*   papers     = (const int*)d_in[3];
    const int*   like_src   = (const int*)d_in[4];
    const int*   like_dst   = (const int*)d_in[5];
    const int*   co_src     = (const int*)d_in[6];
    const int*   co_dst     = (const int*)d_in[7];

    // ---- workspace carve-up (256B aligned) ----
    size_t off = 0;
    auto alloc = [&](size_t bytes) -> void* {
        void* p = (char*)d_ws + off;
        off += (bytes + 255) & ~(size_t)255;
        return p;
    };
    int* deg_ls = (int*)alloc((size_t)NAUTH * 4);
    int* deg_ld = (int*)alloc((size_t)NPAP  * 4);
    int* deg_cs = (int*)alloc((size_t)NAUTH * 4);
    int* deg_cd = (int*)alloc((size_t)NAUTH * 4);
    size_t deg_bytes = off;

    int* cur_ls = (int*)alloc((size_t)NAUTH * 4);
    int* cur_ld = (int*)alloc((size_t)NPAP  * 4);
    int* cur_cd = (int*)alloc((size_t)NAUTH * 4);
    int* bsum_ls = (int*)alloc(1024);
    int* bsum_ld = (int*)alloc(1024);
    int* bsum_cd = (int*)alloc(1024);
    int2* pairs_ls = (int2*)alloc((size_t)ELIKE * 8);
    int2* pairs_ld = (int2*)alloc((size_t)ELIKE * 8);
    int2* pairs_cd = (int2*)alloc((size_t)ECO   * 8);

    float* co_a1 = (float*)alloc((size_t)NAUTH * DIM * 4);
    float* wr_a1 = (float*)alloc((size_t)NAUTH * DIM * 4);
    float* wr_p1 = (float*)alloc((size_t)NPAP  * DIM * 4);
    float* a2buf = (float*)alloc((size_t)NAUTH * DIM * 4);

    float* out_pred = (float*)d_out;               // [B]
    float* out_a    = out_pred + BATCH;            // [B,D]
    float* out_p    = out_a + (size_t)BATCH * DIM; // [B,D]

    const int nb_ls = (NAUTH + SCAN_CHUNK - 1) / SCAN_CHUNK;  // 98
    const int nb_ld = (NPAP  + SCAN_CHUNK - 1) / SCAN_CHUNK;  // 196
    const int nb_cd = nb_ls;

    // ---- degrees ----
    hipMemsetAsync(d_ws, 0, deg_bytes, stream);
    degree_kernel<<<2344, 256, 0, stream>>>(like_src, like_dst, co_src, co_dst,
                                            deg_ls, deg_ld, deg_cs, deg_cd);

    // ---- exclusive scans -> cursors ----
    scan_block_sums<<<nb_ls, 256, 0, stream>>>(deg_ls, bsum_ls, NAUTH);
    scan_block_sums<<<nb_ld, 256, 0, stream>>>(deg_ld, bsum_ld, NPAP);
    scan_block_sums<<<nb_cd, 256, 0, stream>>>(deg_cd, bsum_cd, NAUTH);
    scan_serial<<<1, 64, 0, stream>>>(bsum_ls, nb_ls);
    scan_serial<<<1, 64, 0, stream>>>(bsum_ld, nb_ld);
    scan_serial<<<1, 64, 0, stream>>>(bsum_cd, nb_cd);
    scan_write_cur<<<nb_ls, 256, 0, stream>>>(deg_ls, bsum_ls, cur_ls, NAUTH);
    scan_write_cur<<<nb_ld, 256, 0, stream>>>(deg_ld, bsum_ld, cur_ld, NPAP);
    scan_write_cur<<<nb_cd, 256, 0, stream>>>(deg_cd, bsum_cd, cur_cd, NAUTH);

    // ---- counting-sort placement (coefs computed inline) ----
    placement_kernel<<<2344, 256, 0, stream>>>(like_src, like_dst, co_src, co_dst,
                                               deg_ls, deg_ld, deg_cs, deg_cd,
                                               cur_ls, cur_ld, cur_cd,
                                               pairs_ls, pairs_ld, pairs_cd);

    // ---- layer 1 (segmented gathers; inits fused, no memsets) ----
    l1_author_kernel<<<(NAUTH + 3) / 4, 256, 0, stream>>>(
        author_emb, paper_emb,
        cur_cd, deg_cd, pairs_cd, cur_ls, deg_ls, pairs_ls,
        co_a1, wr_a1);
    l1_paper_kernel<<<(NPAP + 3) / 4, 256, 0, stream>>>(
        author_emb, paper_emb, cur_ld, deg_ld, pairs_ld, wr_p1);

    // ---- layer 2 (fused author pass; 0.5 folded; _wr_p2 dead) ----
    l2_author_kernel<<<(NAUTH + 3) / 4, 256, 0, stream>>>(
        co_a1, wr_a1, wr_p1,
        cur_cd, deg_cd, pairs_cd, cur_ls, deg_ls, pairs_ls,
        a2buf);

    // ---- scoring ----
    final_kernel<<<4096, 256, 0, stream>>>(author_emb, paper_emb, authors, papers,
                                           co_a1, wr_a1, a2buf,
                                           out_pred, out_a, out_p);
}

// Round 13
// 748.946 us; speedup vs baseline: 3.7893x; 1.1016x over previous
//
#include <hip/hip_runtime.h>
#include <math.h>

#define NAUTH 100000
#define NPAP  200000
#define DIM   128
#define ELIKE 600000
#define ECO   600000
#define BATCH 16384
#define EPSW  1e-8f

static_assert(ELIKE == ECO, "degree kernel assumes equal edge counts");

// ===========================================================================
// Stage 1: integer degree histograms.
// ===========================================================================
__global__ __launch_bounds__(256) void degree_kernel(
    const int* __restrict__ like_src, const int* __restrict__ like_dst,
    const int* __restrict__ co_src,   const int* __restrict__ co_dst,
    int* __restrict__ deg_ls, int* __restrict__ deg_ld,
    int* __restrict__ deg_cs, int* __restrict__ deg_cd)
{
    int stride = gridDim.x * blockDim.x;
    for (int i = blockIdx.x * blockDim.x + threadIdx.x; i < ELIKE; i += stride) {
        atomicAdd(&deg_ls[like_src[i]], 1);
        atomicAdd(&deg_ld[like_dst[i]], 1);
        atomicAdd(&deg_cs[co_src[i]],   1);
        atomicAdd(&deg_cd[co_dst[i]],   1);
    }
}

// ===========================================================================
// Stage 2: 3-stage exclusive scan of a degree array -> segment cursors.
// ===========================================================================
#define SCAN_CHUNK 1024

__global__ __launch_bounds__(256) void scan_block_sums(
    const int* __restrict__ deg, int* __restrict__ bsum, int n)
{
    __shared__ int sd[256];
    int t = threadIdx.x;
    int base = blockIdx.x * SCAN_CHUNK + t * 4;
    int s = 0;
    #pragma unroll
    for (int j = 0; j < 4; ++j) { int idx = base + j; if (idx < n) s += deg[idx]; }
    sd[t] = s; __syncthreads();
    for (int o = 128; o > 0; o >>= 1) { if (t < o) sd[t] += sd[t + o]; __syncthreads(); }
    if (t == 0) bsum[blockIdx.x] = sd[0];
}

__global__ void scan_serial(int* __restrict__ bsum, int nb)
{
    if (threadIdx.x == 0 && blockIdx.x == 0) {
        int run = 0;
        for (int i = 0; i < nb; ++i) { int v = bsum[i]; bsum[i] = run; run += v; }
    }
}

__global__ __launch_bounds__(256) void scan_write_cur(
    const int* __restrict__ deg, const int* __restrict__ bsum,
    int* __restrict__ cur, int n)
{
    __shared__ int sd[256];
    int t = threadIdx.x;
    int base = blockIdx.x * SCAN_CHUNK + t * 4;
    int d[4]; int s = 0;
    #pragma unroll
    for (int j = 0; j < 4; ++j) {
        int idx = base + j;
        d[j] = (idx < n) ? deg[idx] : 0;
        s += d[j];
    }
    sd[t] = s; __syncthreads();
    for (int o = 1; o < 256; o <<= 1) {
        int v = (t >= o) ? sd[t - o] : 0;
        __syncthreads();
        sd[t] += v;
        __syncthreads();
    }
    int excl = sd[t] - s + bsum[blockIdx.x];
    #pragma unroll
    for (int j = 0; j < 4; ++j) {
        int idx = base + j;
        if (idx < n) { cur[idx] = excl; excl += d[j]; }
    }
}

// ===========================================================================
// Stage 3: counting-sort placement with inline coef computation.
// After this kernel, cur[n] == segment_end(n); start = cur[n] - deg[n].
// ===========================================================================
__global__ __launch_bounds__(256) void placement_kernel(
    const int* __restrict__ like_src, const int* __restrict__ like_dst,
    const int* __restrict__ co_src,   const int* __restrict__ co_dst,
    const int* __restrict__ deg_ls, const int* __restrict__ deg_ld,
    const int* __restrict__ deg_cs, const int* __restrict__ deg_cd,
    int* __restrict__ cur_ls, int* __restrict__ cur_ld, int* __restrict__ cur_cd,
    int2* __restrict__ pairs_ls, int2* __restrict__ pairs_ld,
    int2* __restrict__ pairs_cd)
{
    int stride = gridDim.x * blockDim.x;
    for (int i = blockIdx.x * blockDim.x + threadIdx.x; i < ELIKE; i += stride) {
        int ls = like_src[i], ld = like_dst[i];
        float lc = 1.0f / sqrtf(fmaxf((float)deg_ls[ls] * (float)deg_ld[ld], 1.0f));
        int lcb = __float_as_int(lc);
        int s1 = atomicAdd(&cur_ls[ls], 1);
        pairs_ls[s1] = make_int2(ld, lcb);          // by like_src, gather paper
        int s2 = atomicAdd(&cur_ld[ld], 1);
        pairs_ld[s2] = make_int2(ls, lcb);          // by like_dst, gather author

        int cs = co_src[i], cd = co_dst[i];
        float cc = 1.0f / sqrtf(fmaxf((float)deg_cs[cs] * (float)deg_cd[cd], 1.0f));
        int s3 = atomicAdd(&cur_cd[cd], 1);
        pairs_cd[s3] = make_int2(cs, __float_as_int(cc)); // by co_dst, gather author
    }
}

// ===========================================================================
// Segmented gather v2: half-wave float4, 2 edges per step, 2 independent
// accumulator chains (4 loads in flight per wave). Lanes 0-31 = half 0
// (edges k, k+2), lanes 32-63 = half 1 (edges k+1, k+3). Tails are
// exec-mask predicated (no wasted fetches). Caller must cross-half reduce.
// ===========================================================================
__device__ __forceinline__ void seg_acc4(
    const int2* __restrict__ pairs, int start, int end, int lane,
    int half, int sub, const float* __restrict__ src,
    float4& acca, float4& accb)
{
    for (int base = start; base < end; base += 64) {
        int m = end - base; if (m > 64) m = 64;
        int2 pr = make_int2(0, 0);
        if (lane < m) pr = pairs[base + lane];
        for (int k = 0; k < m; k += 4) {
            int kk0 = k + half;
            int kk1 = k + 2 + half;
            int   g0 = __shfl(pr.x, kk0);
            float c0 = __int_as_float(__shfl(pr.y, kk0));
            int   g1 = __shfl(pr.x, kk1);
            float c1 = __int_as_float(__shfl(pr.y, kk1));
            if (kk0 < m) {
                float4 v = ((const float4*)(src + (size_t)g0 * DIM))[sub];
                acca.x += v.x * c0; acca.y += v.y * c0;
                acca.z += v.z * c0; acca.w += v.w * c0;
            }
            if (kk1 < m) {
                float4 v = ((const float4*)(src + (size_t)g1 * DIM))[sub];
                accb.x += v.x * c1; accb.y += v.y * c1;
                accb.z += v.z * c1; accb.w += v.w * c1;
            }
        }
    }
}

// combine the two chains + cross-half reduce; both halves end with the total
__device__ __forceinline__ float4 xh_reduce(float4 a, float4 b)
{
    float4 r;
    r.x = a.x + b.x; r.y = a.y + b.y; r.z = a.z + b.z; r.w = a.w + b.w;
    r.x += __shfl_xor(r.x, 32);
    r.y += __shfl_xor(r.y, 32);
    r.z += __shfl_xor(r.z, 32);
    r.w += __shfl_xor(r.w, 32);
    return r;
}

// ===========================================================================
// Layer-1 fused kernel (authors AND papers in one grid, node-range split):
//   author n : co_a1[n] = sum(co);  wr_a1[n] = u_sw*emb + sum(like by src)
//   paper  n : wr_p1[n] = i_sw*emb + sum(like by dst)
// ===========================================================================
__global__ __launch_bounds__(256) void l1_kernel(
    const float* __restrict__ author_emb, const float* __restrict__ paper_emb,
    const int* __restrict__ cur_cd, const int* __restrict__ deg_cd,
    const int2* __restrict__ pairs_cd,
    const int* __restrict__ cur_ls, const int* __restrict__ deg_ls,
    const int2* __restrict__ pairs_ls,
    const int* __restrict__ cur_ld, const int* __restrict__ deg_ld,
    const int2* __restrict__ pairs_ld,
    float* __restrict__ co_a1, float* __restrict__ wr_a1,
    float* __restrict__ wr_p1)
{
    int lane = threadIdx.x & 63;
    int half = lane >> 5;
    int sub  = lane & 31;
    int wid  = blockIdx.x * (blockDim.x >> 6) + (threadIdx.x >> 6);

    if (wid < NAUTH) {
        int n = wid;
        float4 ca = make_float4(0.f,0.f,0.f,0.f), cb = ca;
        float4 wa = ca, wb = ca;
        int ec = cur_cd[n], dc = deg_cd[n];
        seg_acc4(pairs_cd, ec - dc, ec, lane, half, sub, author_emb, ca, cb);
        int el = cur_ls[n], dl = deg_ls[n];
        seg_acc4(pairs_ls, el - dl, el, lane, half, sub, paper_emb, wa, wb);

        float4 cacc = xh_reduce(ca, cb);
        float4 wacc = xh_reduce(wa, wb);
        if (half == 0) {
            float d  = (float)dl;
            float sw = 1.0f - d / (d + EPSW);
            float4 base = ((const float4*)(author_emb + (size_t)n * DIM))[sub];
            float4 wr;
            wr.x = sw * base.x + wacc.x;
            wr.y = sw * base.y + wacc.y;
            wr.z = sw * base.z + wacc.z;
            wr.w = sw * base.w + wacc.w;
            ((float4*)(co_a1 + (size_t)n * DIM))[sub] = cacc;
            ((float4*)(wr_a1 + (size_t)n * DIM))[sub] = wr;
        }
    } else {
        int n = wid - NAUTH;
        if (n >= NPAP) return;
        float4 pa = make_float4(0.f,0.f,0.f,0.f), pb = pa;
        int e = cur_ld[n], dg = deg_ld[n];
        seg_acc4(pairs_ld, e - dg, e, lane, half, sub, author_emb, pa, pb);

        float4 acc = xh_reduce(pa, pb);
        if (half == 0) {
            float d  = (float)dg;
            float sw = 1.0f - d / (d + EPSW);
            float4 base = ((const float4*)(paper_emb + (size_t)n * DIM))[sub];
            acc.x += sw * base.x;
            acc.y += sw * base.y;
            acc.z += sw * base.z;
            acc.w += sw * base.w;
            ((float4*)(wr_p1 + (size_t)n * DIM))[sub] = acc;
        }
    }
}

// ===========================================================================
// Layer-2 author pass (fused, *0.5 folded):
//   a2buf[n] = 0.5*( u_sw*wr_a1[n] + sum(co: co_a1) + sum(like: wr_p1) )
// ===========================================================================
__global__ __launch_bounds__(256) void l2_author_kernel(
    const float* __restrict__ co_a1, const float* __restrict__ wr_a1,
    const float* __restrict__ wr_p1,
    const int* __restrict__ cur_cd, const int* __restrict__ deg_cd,
    const int2* __restrict__ pairs_cd,
    const int* __restrict__ cur_ls, const int* __restrict__ deg_ls,
    const int2* __restrict__ pairs_ls,
    float* __restrict__ a2buf)
{
    int lane = threadIdx.x & 63;
    int half = lane >> 5;
    int sub  = lane & 31;
    int n = blockIdx.x * (blockDim.x >> 6) + (threadIdx.x >> 6);
    if (n >= NAUTH) return;

    float4 aa = make_float4(0.f,0.f,0.f,0.f), ab = aa;
    int ec = cur_cd[n], dc = deg_cd[n];
    seg_acc4(pairs_cd, ec - dc, ec, lane, half, sub, co_a1, aa, ab);
    int el = cur_ls[n], dl = deg_ls[n];
    seg_acc4(pairs_ls, el - dl, el, lane, half, sub, wr_p1, aa, ab);

    float4 acc = xh_reduce(aa, ab);
    if (half == 0) {
        float d  = (float)dl;
        float sw = 1.0f - d / (d + EPSW);
        float4 base = ((const float4*)(wr_a1 + (size_t)n * DIM))[sub];
        acc.x = 0.5f * (acc.x + sw * base.x);
        acc.y = 0.5f * (acc.y + sw * base.y);
        acc.z = 0.5f * (acc.z + sw * base.z);
        acc.w = 0.5f * (acc.w + sw * base.w);
        ((float4*)(a2buf + (size_t)n * DIM))[sub] = acc;
    }
}

// ===========================================================================
// Final scoring: one wave per batch element; full final_author never built.
// ===========================================================================
__global__ __launch_bounds__(256) void final_kernel(
    const float* __restrict__ author_emb, const float* __restrict__ paper_emb,
    const int* __restrict__ authors, const int* __restrict__ papers,
    const float* __restrict__ co_a1, const float* __restrict__ wr_a1,
    const float* __restrict__ a2buf,
    float* __restrict__ out_pred, float* __restrict__ out_a, float* __restrict__ out_p)
{
    int lane  = threadIdx.x & 63;
    int wpb   = blockDim.x >> 6;
    int wave0 = blockIdx.x * wpb + (threadIdx.x >> 6);
    int wstr  = gridDim.x * wpb;
    for (int b = wave0; b < BATCH; b += wstr) {
        int a = authors[b];
        int p = papers[b];
        size_t arow = (size_t)a * DIM;
        size_t prow = (size_t)p * DIM;
        float2 e  = ((const float2*)(author_emb + arow))[lane];
        float2 c1 = ((const float2*)(co_a1 + arow))[lane];
        float2 w1 = ((const float2*)(wr_a1 + arow))[lane];
        float2 a2 = ((const float2*)(a2buf + arow))[lane];
        float fx = e.x + 0.5f * c1.x + 0.5f * w1.x + a2.x;
        float fy = e.y + 0.5f * c1.y + 0.5f * w1.y + a2.y;
        float2 pp = ((const float2*)(paper_emb + prow))[lane];
        ((float2*)(out_a + (size_t)b * DIM))[lane] = make_float2(fx, fy);
        ((float2*)(out_p + (size_t)b * DIM))[lane] = pp;
        float dot = fx * pp.x + fy * pp.y;
        #pragma unroll
        for (int off = 32; off; off >>= 1) dot += __shfl_xor(dot, off);
        if (lane == 0) out_pred[b] = 1.0f / (1.0f + expf(-dot));
    }
}

extern "C" void kernel_launch(void* const* d_in, const int* in_sizes, int n_in,
                              void* d_out, int out_size, void* d_ws, size_t ws_size,
                              hipStream_t stream) {
    const float* author_emb = (const float*)d_in[0];
    const float* paper_emb  = (const float*)d_in[1];
    const int*   authors    = (const int*)d_in[2];
    const int*   papers     = (const int*)d_in[3];
    const int*   like_src   = (const int*)d_in[4];
    const int*   like_dst   = (const int*)d_in[5];
    const int*   co_src     = (const int*)d_in[6];
    const int*   co_dst     = (const int*)d_in[7];

    // ---- workspace carve-up (256B aligned) ----
    size_t off = 0;
    auto alloc = [&](size_t bytes) -> void* {
        void* p = (char*)d_ws + off;
        off += (bytes + 255) & ~(size_t)255;
        return p;
    };
    int* deg_ls = (int*)alloc((size_t)NAUTH * 4);
    int* deg_ld = (int*)alloc((size_t)NPAP  * 4);
    int* deg_cs = (int*)alloc((size_t)NAUTH * 4);
    int* deg_cd = (int*)alloc((size_t)NAUTH * 4);
    size_t deg_bytes = off;

    int* cur_ls = (int*)alloc((size_t)NAUTH * 4);
    int* cur_ld = (int*)alloc((size_t)NPAP  * 4);
    int* cur_cd = (int*)alloc((size_t)NAUTH * 4);
    int* bsum_ls = (int*)alloc(1024);
    int* bsum_ld = (int*)alloc(1024);
    int* bsum_cd = (int*)alloc(1024);
    int2* pairs_ls = (int2*)alloc((size_t)ELIKE * 8);
    int2* pairs_ld = (int2*)alloc((size_t)ELIKE * 8);
    int2* pairs_cd = (int2*)alloc((size_t)ECO   * 8);

    float* co_a1 = (float*)alloc((size_t)NAUTH * DIM * 4);
    float* wr_a1 = (float*)alloc((size_t)NAUTH * DIM * 4);
    float* wr_p1 = (float*)alloc((size_t)NPAP  * DIM * 4);
    float* a2buf = (float*)alloc((size_t)NAUTH * DIM * 4);

    float* out_pred = (float*)d_out;               // [B]
    float* out_a    = out_pred + BATCH;            // [B,D]
    float* out_p    = out_a + (size_t)BATCH * DIM; // [B,D]

    const int nb_ls = (NAUTH + SCAN_CHUNK - 1) / SCAN_CHUNK;  // 98
    const int nb_ld = (NPAP  + SCAN_CHUNK - 1) / SCAN_CHUNK;  // 196
    const int nb_cd = nb_ls;

    // ---- degrees ----
    hipMemsetAsync(d_ws, 0, deg_bytes, stream);
    degree_kernel<<<2344, 256, 0, stream>>>(like_src, like_dst, co_src, co_dst,
                                            deg_ls, deg_ld, deg_cs, deg_cd);

    // ---- exclusive scans -> cursors ----
    scan_block_sums<<<nb_ls, 256, 0, stream>>>(deg_ls, bsum_ls, NAUTH);
    scan_block_sums<<<nb_ld, 256, 0, stream>>>(deg_ld, bsum_ld, NPAP);
    scan_block_sums<<<nb_cd, 256, 0, stream>>>(deg_cd, bsum_cd, NAUTH);
    scan_serial<<<1, 64, 0, stream>>>(bsum_ls, nb_ls);
    scan_serial<<<1, 64, 0, stream>>>(bsum_ld, nb_ld);
    scan_serial<<<1, 64, 0, stream>>>(bsum_cd, nb_cd);
    scan_write_cur<<<nb_ls, 256, 0, stream>>>(deg_ls, bsum_ls, cur_ls, NAUTH);
    scan_write_cur<<<nb_ld, 256, 0, stream>>>(deg_ld, bsum_ld, cur_ld, NPAP);
    scan_write_cur<<<nb_cd, 256, 0, stream>>>(deg_cd, bsum_cd, cur_cd, NAUTH);

    // ---- counting-sort placement (coefs computed inline) ----
    placement_kernel<<<2344, 256, 0, stream>>>(like_src, like_dst, co_src, co_dst,
                                               deg_ls, deg_ld, deg_cs, deg_cd,
                                               cur_ls, cur_ld, cur_cd,
                                               pairs_ls, pairs_ld, pairs_cd);

    // ---- layer 1 (merged author+paper grid; gather engine v2) ----
    l1_kernel<<<(NAUTH + NPAP + 3) / 4, 256, 0, stream>>>(
        author_emb, paper_emb,
        cur_cd, deg_cd, pairs_cd,
        cur_ls, deg_ls, pairs_ls,
        cur_ld, deg_ld, pairs_ld,
        co_a1, wr_a1, wr_p1);

    // ---- layer 2 (fused author pass; 0.5 folded; _wr_p2 dead) ----
    l2_author_kernel<<<(NAUTH + 3) / 4, 256, 0, stream>>>(
        co_a1, wr_a1, wr_p1,
        cur_cd, deg_cd, pairs_cd, cur_ls, deg_ls, pairs_ls,
        a2buf);

    // ---- scoring ----
    final_kernel<<<4096, 256, 0, stream>>>(author_emb, paper_emb, authors, papers,
                                           co_a1, wr_a1, a2buf,
                                           out_pred, out_a, out_p);
}